// Round 16
// baseline (127.699 us; speedup 1.0000x reference)
//
#include <hip/hip_runtime.h>
#include <hip/hip_bf16.h>

// Problem constants (from reference): B=8, T=4096, E=16, H=64
#define BB 8
#define TT 4096
#define EE 16
#define HH 64
#define ZT 16      // colsum t-chunk split: 2048 blocks = 8/CU
#define NS 8       // out_mfma s-slice split: 2048 blocks = 8/CU

typedef __attribute__((ext_vector_type(8))) __bf16 bf16x8;   // MFMA A/B frag (4 VGPRs)
typedef __attribute__((ext_vector_type(4))) __bf16 bf16x4;   // packed 8B
typedef __attribute__((ext_vector_type(4))) float f32x4;     // 16x16 C/D frag
typedef __attribute__((ext_vector_type(16))) float f32x16;   // 32x32 C/D frag

// R23 exp (validated, absmax-stable): integer-log + cubic Taylor about L0=5.5.
//   t = L - 5.5 = fma(cvt(bitcast(d)), 2^-23, -132.4427)
//   g ~= 2.198973 - 7.50666e-2 t + 2.90731e-3 t^2 - 9.35706e-5 t^3
static __device__ __forceinline__ float exp_pow16_fast(float d) {
    unsigned di = __builtin_bit_cast(unsigned, d);
    float t = __builtin_fmaf((float)di, 0x1p-23f, -132.4427f);
    float r = __builtin_fmaf(t, -9.35706e-5f, 2.90731e-3f);
    r = __builtin_fmaf(t, r, -7.50666e-2f);
    r = __builtin_fmaf(t, r, 2.198973f);
    return r;
}

// ---- kernel 1: rank-16 factorization (R11) + zero Dsum ---------------------
__global__ __launch_bounds__(256) void proj_kernel(
        const float* __restrict__ x, const float* __restrict__ Wq,
        const float* __restrict__ Wk,
        __bf16* __restrict__ Yb, __bf16* __restrict__ xb,
        float* __restrict__ Dsum) {
    __shared__ float Ms[16][16];
    __shared__ float xs[16][16];
    int tid = threadIdx.x;
    size_t gid = (size_t)blockIdx.x * 256 + tid;
    if (gid < (size_t)BB * TT / 4)
        ((float4*)Dsum)[gid] = (float4){0.f, 0.f, 0.f, 0.f};
    int i = tid >> 4, j = tid & 15;
    float m = 0.f;
#pragma unroll 8
    for (int h = 0; h < HH; ++h) m += Wq[i * HH + h] * Wk[j * HH + h];
    Ms[i][j] = m;
    int row0 = blockIdx.x * 16;
    xs[i][j] = x[(size_t)(row0 + i) * EE + j];   // 256 consecutive floats
    __syncthreads();
    float y = 0.f;
#pragma unroll
    for (int k = 0; k < EE; ++k) y += xs[i][k] * Ms[k][j];
    size_t idx = (size_t)(row0 + i) * EE + j;
    Yb[idx] = (__bf16)y;
    xb[idx] = (__bf16)xs[i][j];
}

// ---- kernel 2: Dsum[b][s] += sum_{t in chunk z} exp((Y_t·x_s)^(-1/16)) -----
// R16/R20/R21/R23 (proven 127.1): 32x32x16 MFMA K=16 exact; integer-log +
// cubic, constant hoisted (last fma = accumulator); setprio cluster.
__global__ __launch_bounds__(256) void colsum_mfma(
        const __bf16* __restrict__ Yb, const __bf16* __restrict__ xb,
        float* __restrict__ Dsum) {
    int lane = threadIdx.x & 63;
    int w = threadIdx.x >> 6;
    int wl = lane & 31;
    int hi = lane >> 5;
    int b = blockIdx.y;
    int z = blockIdx.z;
    int s0 = blockIdx.x * 256 + w * 64;      // wave owns 64 s = 2 x 32-s groups

    const __bf16* xbb = xb + (size_t)b * TT * EE;
    const __bf16* Ybb = Yb + (size_t)b * TT * EE;

    bf16x8 bx[2];
#pragma unroll
    for (int sg = 0; sg < 2; ++sg)
        bx[sg] = *(const bf16x8*)(xbb + (size_t)(s0 + sg * 32 + wl) * EE + hi * 8);

    const __bf16* gya = Ybb + (size_t)wl * EE + hi * 8;

    const int TL = TT / ZT;                  // 256 t per block -> 8 stages of 32
    int t0 = z * TL, tend = t0 + TL;

    float csum[2] = {0.f, 0.f};

    auto BODY = [&](bf16x8 ya) {
        __builtin_amdgcn_s_setprio(1);
#pragma unroll
        for (int sg = 0; sg < 2; ++sg) {
            f32x16 c = {};
            c = __builtin_amdgcn_mfma_f32_32x32x16_bf16(ya, bx[sg], c, 0, 0, 0);
#pragma unroll
            for (int r = 0; r < 16; ++r) {
                unsigned di = __builtin_bit_cast(unsigned, c[r]);
                float t = __builtin_fmaf((float)di, 0x1p-23f, -132.4427f);
                float p = __builtin_fmaf(t, -9.35706e-5f, 2.90731e-3f);
                p = __builtin_fmaf(t, p, -7.50666e-2f);
                csum[sg] = __builtin_fmaf(t, p, csum[sg]);
            }
        }
        __builtin_amdgcn_s_setprio(0);
    };

    bf16x8 yaA, yaB;
    yaA = *(const bf16x8*)(gya + (size_t)t0 * EE);
    for (int t = t0; t < tend; t += 64) {     // TL % 64 == 0
        yaB = *(const bf16x8*)(gya + (size_t)(t + 32) * EE);
        BODY(yaA);
        int tn = (t + 64 < tend) ? (t + 64) : t0;   // last: dummy reload
        yaA = *(const bf16x8*)(gya + (size_t)tn * EE);
        BODY(yaB);
    }

#pragma unroll
    for (int sg = 0; sg < 2; ++sg) {
        float r = csum[sg];
        r += __shfl_xor(r, 32, 64);
        if (lane < 32)
            atomicAdd(&Dsum[(size_t)b * TT + s0 + sg * 32 + wl],
                      r + 256.0f * 2.198973f);
    }
}

// ---- kernel 3: xDT[b][e][s] = bf16(x[s][e] / Dsum[b][s]); zero Z -----------
__global__ __launch_bounds__(256) void xd_kernel(
        const __bf16* __restrict__ xb, const float* __restrict__ Dsum,
        __bf16* __restrict__ xDT, float* __restrict__ Z) {
    __shared__ float Rs[64];
    __shared__ __bf16 tt[16][68];
    int b = blockIdx.y;
    int s0 = blockIdx.x * 64;
    int tid = threadIdx.x;
    size_t zi = ((size_t)b * gridDim.x + blockIdx.x) * 256 + tid;
    ((float4*)Z)[zi] = (float4){0.f, 0.f, 0.f, 0.f};
    if (tid < 64)
        Rs[tid] = 1.0f / Dsum[(size_t)b * TT + s0 + tid];   // coalesced
    __syncthreads();
    int sl = tid & 63, eg = tid >> 6;        // e-range eg*4..+3
    bf16x4 v = *(const bf16x4*)(xb + ((size_t)b * TT + s0 + sl) * EE + eg * 4);
    float r = Rs[sl];
#pragma unroll
    for (int i = 0; i < 4; ++i) tt[eg * 4 + i][sl] = (__bf16)((float)v[i] * r);
    __syncthreads();
    int e = tid >> 4, sc = tid & 15;
    *(bf16x4*)(xDT + ((size_t)b * EE + e) * TT + s0 + sc * 4) = *(const bf16x4*)&tt[e][sc * 4];
}

// ---- kernel 4: Z[b][t][e] += sum_{s in slice z} exp(S_ts) * xDT[e][s] ------
// R24: STAGE split into QK (-> c regs) and EXPW (c -> Etile); per-stage order
//   QK(k+1) ; PV(k) ; EXPW(k+1)
// fixes two couplings of the old order (STAGE then PV):
//  (1) in-order per-wave DS queue made PV(k)'s ds_read wait for exp(k+1)'s
//      ds_writes — the double buffer bought correctness distance, not time;
//  (2) the QK->exp MFMA-latency gap had no same-wave filler; now PV(k)'s
//      ds_read + 2 MFMAs sit in it.
// WAR safety: PV(k) reads buf[k%2] before EXPW(k+2) writes it (same wave,
// in-order DS). Zero barriers (Etile wave-private). R20 setprio kept.
__global__ __launch_bounds__(256) void out_mfma(
        const __bf16* __restrict__ Yb, const __bf16* __restrict__ xb,
        const __bf16* __restrict__ xDT, float* __restrict__ Z) {
    __shared__ __bf16 Etile[2][4][32 * 36]; // [buf][wave] E[t 32][s 32 pad4]

    int lane = threadIdx.x & 63;
    int w = threadIdx.x >> 6;
    int wl = lane & 31;
    int hi = lane >> 5;
    int quad = lane >> 4;                    // for PV (16x16 frags)
    int l15 = lane & 15;
    int b = blockIdx.y;
    int z = blockIdx.z;
    int t0 = blockIdx.x * 128 + w * 32;      // wave owns one 32-t tile

    const __bf16* xbb = xb + (size_t)b * TT * EE;
    const __bf16* Ybb = Yb + (size_t)b * TT * EE;
    const __bf16* xdb = xDT + (size_t)b * EE * TT;

    // persistent B of S^T: B[k=e][n=t]: lane holds Y[t0+wl][hi*8..+7] (no pad)
    bf16x8 yf = *(const bf16x8*)(Ybb + (size_t)(t0 + wl) * EE + hi * 8);

    f32x4 acc[2] = {{0.f, 0.f, 0.f, 0.f}, {0.f, 0.f, 0.f, 0.f}};

    // streamed A of S^T: xb[s+wl][hi*8..+7] (16B)
    const __bf16* gaf = xbb + (size_t)wl * EE + hi * 8;
    // PV B: B[k=s_loc=quad*8+j][n=e=l15] = xDT[e=l15][s+quad*8..+7]
    const __bf16* gxd = xdb + (size_t)l15 * TT + quad * 8;

    const int SL = TT / NS;                  // 512 s -> 16 stages of 32 s
    int s0z = z * SL, send = s0z + SL;

    auto LOADF = [&](bf16x8& af, bf16x8& bxd, int s) {
        af = *(const bf16x8*)(gaf + (size_t)s * EE);
        bxd = *(const bf16x8*)(gxd + s);
    };
    auto QK = [&](bf16x8 af) -> f32x16 {     // S^T tile into regs
        f32x16 c = {};
        return __builtin_amdgcn_mfma_f32_32x32x16_bf16(af, yf, c, 0, 0, 0);
    };
    auto EXPW = [&](const f32x16& c, int p) { // exp(c) -> Etile[p]
        __builtin_amdgcn_s_setprio(1);
        // E[t=wl][s = 8*g + 4*hi .. +3] from reg quartet g
#pragma unroll
        for (int g = 0; g < 4; ++g) {
            bf16x4 e;
#pragma unroll
            for (int r = 0; r < 4; ++r)
                e[r] = (__bf16)exp_pow16_fast(c[g * 4 + r]);
            *(bf16x4*)&Etile[p][w][wl * 36 + g * 8 + hi * 4] = e;
        }
        __builtin_amdgcn_s_setprio(0);
    };
    auto PV = [&](bf16x8& bxd, int p) {
        __builtin_amdgcn_s_setprio(1);
#pragma unroll
        for (int h2 = 0; h2 < 2; ++h2) {
            // A[m=t=h2*16+l15][k=s=quad*8+j] from Etile[p] — contiguous b128
            bf16x8 aE = *(const bf16x8*)&Etile[p][w][(h2 * 16 + l15) * 36 + quad * 8];
            acc[h2] = __builtin_amdgcn_mfma_f32_16x16x32_bf16(aE, bxd, acc[h2], 0, 0, 0);
        }
        __builtin_amdgcn_s_setprio(0);
    };

    bf16x8 afA, afB, bxdA, bxdB;
    f32x16 cA, cB;
    LOADF(afA, bxdA, s0z);                   // stage 0 operands
    cA = QK(afA);
    EXPW(cA, 0);                             // prologue: buf0 = stage 0
    for (int s = s0z; s < send; s += 64) {   // SL % 64 == 0; stages 2j, 2j+1
        LOADF(afB, bxdB, s + 32);            // stage k+1 operands
        cB = QK(afB);                        // QK(k+1) issued early
        PV(bxdA, 0);                         // PV(k): fills QK latency, clean DS queue
        EXPW(cB, 1);                         // exp(k+1) -> buf1
        int sn = (s + 64 < send) ? (s + 64) : s0z;   // last: dummy stage
        LOADF(afA, bxdA, sn);                // stage k+2 operands
        cA = QK(afA);                        // QK(k+2)
        PV(bxdB, 1);                         // PV(k+1)
        EXPW(cA, 0);                         // exp(k+2) -> buf0 (after PV(k) read: WAR ok)
    }

    // Z[t][e]: t = t0 + h2*16 + quad*4 + r, e = l15 (NS contributions/address)
    float* zp = Z + ((size_t)b * TT + t0) * EE;
#pragma unroll
    for (int h2 = 0; h2 < 2; ++h2)
#pragma unroll
        for (int r = 0; r < 4; ++r)
            atomicAdd(&zp[(size_t)(h2 * 16 + quad * 4 + r) * EE + l15], acc[h2][r]);
}

// ---- kernel 5: out[b][t][h] = Z[b][t][:] @ Wk ------------------------------
__global__ __launch_bounds__(256) void zout_kernel(
        const float* __restrict__ Z, const float* __restrict__ Wk,
        float* __restrict__ out) {
    __shared__ float zs[64][16];             // 64 t-rows x 16 e (flat-filled)
    int b = blockIdx.y;
    int t0 = blockIdx.x * 64;
    int tid = threadIdx.x;
    ((float4*)zs)[tid] = ((const float4*)(Z + ((size_t)b * TT + t0) * EE))[tid];
    __syncthreads();
    int h = tid & 63, tg = tid >> 6;
    float wcol[16];
#pragma unroll
    for (int e = 0; e < EE; ++e) wcol[e] = Wk[e * HH + h];
    float* ob = out + ((size_t)b * TT + t0) * HH + h;
#pragma unroll
    for (int k = 0; k < 16; ++k) {
        int tl = tg * 16 + k;
        float o = 0.f;
#pragma unroll
        for (int e = 0; e < EE; ++e) o = __builtin_fmaf(zs[tl][e], wcol[e], o);
        ob[(size_t)tl * HH] = o;             // all lanes read same zs row: broadcast
    }
}

extern "C" void kernel_launch(void* const* d_in, const int* in_sizes, int n_in,
                              void* d_out, int out_size, void* d_ws, size_t ws_size,
                              hipStream_t stream) {
    const float* x  = (const float*)d_in[0];
    const float* Wq = (const float*)d_in[1];
    const float* Wk = (const float*)d_in[2];
    // d_in[3] (Wv) unused: reference computes v = x @ Wk (faithful quirk).

    const size_t NE16 = (size_t)BB * TT * EE;    // 524288
    char* wp = (char*)d_ws;
    __bf16* Yb   = (__bf16*)wp;  wp += NE16 * 2;              // 1 MB
    __bf16* xbb  = (__bf16*)wp;  wp += NE16 * 2;              // 1 MB
    __bf16* xDT  = (__bf16*)wp;  wp += NE16 * 2;              // 1 MB
    float*  Dsum = (float*)wp;   wp += (size_t)BB * TT * 4;   // 128 KB
    float*  Zws  = (float*)wp;                                // 2 MB

    float* out = (float*)d_out;

    proj_kernel<<<BB * TT / 16, 256, 0, stream>>>(x, Wq, Wk, Yb, xbb, Dsum);
    colsum_mfma<<<dim3(TT / 256, BB, ZT), 256, 0, stream>>>(Yb, xbb, Dsum);
    xd_kernel<<<dim3(TT / 64, BB), 256, 0, stream>>>(xbb, Dsum, xDT, Zws);
    out_mfma<<<dim3(TT / 128, BB, NS), 256, 0, stream>>>(Yb, xbb, xDT, Zws);
    zout_kernel<<<dim3(TT / 64, BB), 256, 0, stream>>>(Zws, Wk, out);
}